// Round 1
// baseline (13053.018 us; speedup 1.0000x reference)
//
#include <hip/hip_runtime.h>

// ---------------------------------------------------------------------------
// EfficientDet head (FPN + cls/reg heads), fp32 baseline.
// Generic implicit-GEMM conv kernel:
//   out[co, n] = sum_k W[co, k] * im2col[k, n],  n = (b, oh, ow), k = (ci, r, s)
// Tiles: 128(M=co) x 128(N=pix), BK=16, 256 threads, 8x8 micro-tile/thread,
// double-buffered LDS, one __syncthreads per K-step.
// Epilogue: bias, optional BN+ReLU, or direct scatter into [B, anchors, 14].
// ---------------------------------------------------------------------------

constexpr int BM = 128, BN = 128, BK = 16;
constexpr int TOTAL_ANCH = 196416;  // 9 * (128^2 + 64^2 + 32^2 + 16^2 + 8^2)

template <int KS, bool BNRELU, int DD>   // DD=0: NCHW out; DD=4/10: det scatter
__global__ __launch_bounds__(256, 2)
void conv_gemm(const float* __restrict__ X, const float* __restrict__ Wp,
               const float* __restrict__ bias,
               const float* __restrict__ bn_g, const float* __restrict__ bn_b,
               const float* __restrict__ bn_m, const float* __restrict__ bn_v,
               float* __restrict__ Y,
               int Cin, int K, int logS, int logHW, int N, int Cout,
               int abase, int coloff)
{
    const int tid = threadIdx.x;
    const int n0  = blockIdx.x * BN;
    const int co0 = blockIdx.y * BM;
    const int S   = 1 << logS;
    const int HW  = 1 << logHW;

    __shared__ __align__(16) float As[2][BK][BM + 4];
    __shared__ __align__(16) float Bs[2][BK][BN + 4];

    // ---- B-loader precompute: each thread owns ONE pixel column, 8 k-rows ----
    const int n_l = tid & 127;
    const int kb  = tid >> 7;                 // 0 or 1 (even/odd k rows)
    const int n   = n0 + n_l;
    const int b   = n >> logHW;
    const int hw  = n & (HW - 1);
    const int oh  = hw >> logS;
    const int ow  = hw & (S - 1);
    const int xb  = (b * Cin) << logHW;       // base of this batch's input

    // ---- A-loader precompute: float4 along K ----
    const int kq   = tid & 3;                 // which float4 within BK
    const int co_a = tid >> 2;                // 0..63 (second slot +64)

    const int Ksteps = (K + BK - 1) / BK;

    float areg[2][4];
    float breg[8];

    auto loadA = [&](int k0) {
#pragma unroll
        for (int jj = 0; jj < 2; ++jj) {
            const int co_l = co_a + jj * 64;
            const int kk   = k0 + kq * 4;
            if ((co0 + co_l) < Cout && kk < K) {
                const float4 w4 =
                    *reinterpret_cast<const float4*>(&Wp[(co0 + co_l) * K + kk]);
                areg[jj][0] = w4.x; areg[jj][1] = w4.y;
                areg[jj][2] = w4.z; areg[jj][3] = w4.w;
            } else {
                areg[jj][0] = areg[jj][1] = areg[jj][2] = areg[jj][3] = 0.f;
            }
        }
    };

    auto loadB = [&](int k0) {
#pragma unroll
        for (int j = 0; j < 8; ++j) {
            const int k_l = 2 * j + kb;
            const int k   = k0 + k_l;
            float vv = 0.f;
            if (KS == 1) {
                if (k < K) vv = X[xb + (k << logHW) + hw];
            } else {
                const int ci = (int)((unsigned)k / 9u);
                const int rs = k - ci * 9;
                const int r  = (int)((unsigned)rs / 3u);
                const int s  = rs - r * 3;
                const int ih = oh + r - 1;
                const int iw = ow + s - 1;
                if ((unsigned)ih < (unsigned)S && (unsigned)iw < (unsigned)S)
                    vv = X[xb + (ci << logHW) + (ih << logS) + iw];
            }
            breg[j] = vv;
        }
    };

    auto storeA = [&](int buf) {
#pragma unroll
        for (int jj = 0; jj < 2; ++jj)
#pragma unroll
            for (int e = 0; e < 4; ++e)
                As[buf][kq * 4 + e][co_a + jj * 64] = areg[jj][e];
    };
    auto storeB = [&](int buf) {
#pragma unroll
        for (int j = 0; j < 8; ++j)
            Bs[buf][2 * j + kb][n_l] = breg[j];
    };

    float acc[8][8] = {};
    const int tx = tid & 15;   // pixel dir
    const int ty = tid >> 4;   // co dir

    loadA(0);
    loadB(0);

    for (int s = 0; s < Ksteps; ++s) {
        const int buf = s & 1;
        storeA(buf);
        storeB(buf);
        __syncthreads();
        if (s + 1 < Ksteps) { loadA((s + 1) * BK); loadB((s + 1) * BK); }
#pragma unroll
        for (int k = 0; k < BK; ++k) {
            float a[8], bv[8];
            *reinterpret_cast<float4*>(&a[0]) =
                *reinterpret_cast<const float4*>(&As[buf][k][ty * 8]);
            *reinterpret_cast<float4*>(&a[4]) =
                *reinterpret_cast<const float4*>(&As[buf][k][ty * 8 + 4]);
            *reinterpret_cast<float4*>(&bv[0]) =
                *reinterpret_cast<const float4*>(&Bs[buf][k][tx * 8]);
            *reinterpret_cast<float4*>(&bv[4]) =
                *reinterpret_cast<const float4*>(&Bs[buf][k][tx * 8 + 4]);
#pragma unroll
            for (int i = 0; i < 8; ++i)
#pragma unroll
                for (int j = 0; j < 8; ++j)
                    acc[i][j] = fmaf(a[i], bv[j], acc[i][j]);
        }
        // next iteration's stores go to the other buffer; the sync above
        // already guaranteed everyone left compute(s-1) on that buffer.
    }

    // ---- epilogue ----
#pragma unroll
    for (int i = 0; i < 8; ++i) {
        const int co = co0 + ty * 8 + i;
        if (DD > 0 && co >= Cout) break;
        float sc = 1.f, sh;
        const float bi = bias[co];
        if (BNRELU) {
            const float inv = bn_g[co] * rsqrtf(bn_v[co] + 1e-5f);
            sc = inv;
            sh = (bi - bn_m[co]) * inv + bn_b[co];
        } else {
            sh = bi;
        }
#pragma unroll
        for (int j = 0; j < 8; ++j) {
            const int nn = n0 + tx * 8 + j;
            float val = acc[i][j] * sc + sh;
            if (BNRELU) val = fmaxf(val, 0.f);
            const int bb = nn >> logHW;
            const int hh = nn & (HW - 1);
            if (DD > 0) {
                const int a  = co / DD;
                const int cl = co - a * DD;
                Y[(bb * TOTAL_ANCH + abase + hh * 9 + a) * 14 + coloff + cl] = val;
            } else {
                Y[((bb * Cout + co) << logHW) + hh] = val;
            }
        }
    }
}

// fine[b,c,2h,2w] += coarse[b,c,h,w] (nearest 2x upsample add)
__global__ void upsample_add_k(float* __restrict__ fine,
                               const float* __restrict__ coarse,
                               int logSf, int n)
{
    const int i = blockIdx.x * 256 + threadIdx.x;
    if (i >= n) return;
    const int Sf = 1 << logSf;
    const int wf = i & (Sf - 1);
    const int hf = (i >> logSf) & (Sf - 1);
    const int bc = i >> (2 * logSf);
    const int ci = (bc << (2 * (logSf - 1))) + ((hf >> 1) << (logSf - 1)) + (wf >> 1);
    fine[i] += coarse[ci];
}

extern "C" void kernel_launch(void* const* d_in, const int* in_sizes, int n_in,
                              void* d_out, int out_size, void* d_ws, size_t ws_size,
                              hipStream_t stream)
{
    const float* f[5];
    const float* lat_w[5];
    for (int i = 0; i < 5; ++i) f[i] = (const float*)d_in[i];
    for (int i = 0; i < 5; ++i) lat_w[i] = (const float*)d_in[5 + i];
    const float* lat_b  = (const float*)d_in[10];
    const float* fpn_w  = (const float*)d_in[11];
    const float* fpn_b  = (const float*)d_in[12];
    const float* cls_w1 = (const float*)d_in[13];
    const float* cls_b1 = (const float*)d_in[14];
    const float* cls_g  = (const float*)d_in[15];
    const float* cls_bt = (const float*)d_in[16];
    const float* cls_m  = (const float*)d_in[17];
    const float* cls_v  = (const float*)d_in[18];
    const float* cls_w2 = (const float*)d_in[19];
    const float* cls_b2 = (const float*)d_in[20];
    const float* reg_w1 = (const float*)d_in[21];
    const float* reg_b1 = (const float*)d_in[22];
    const float* reg_g  = (const float*)d_in[23];
    const float* reg_bt = (const float*)d_in[24];
    const float* reg_m  = (const float*)d_in[25];
    const float* reg_v  = (const float*)d_in[26];
    const float* reg_w2 = (const float*)d_in[27];
    const float* reg_b2 = (const float*)d_in[28];

    float* out = (float*)d_out;
    float* ws  = (float*)d_ws;

    const int  HW[5]    = {16384, 4096, 1024, 256, 64};
    const int  logS[5]  = {7, 6, 5, 4, 3};
    const int  logHW[5] = {14, 12, 10, 8, 6};
    const int  Cin[5]   = {32, 48, 96, 136, 232};
    const int  abase[5] = {0, 147456, 184320, 193536, 195840};

    // workspace: lat[5] arenas + one max-size fpn scratch (reused per level)
    float* lat[5];
    size_t off = 0;
    for (int i = 0; i < 5; ++i) { lat[i] = ws + off; off += (size_t)8 * 256 * HW[i]; }
    float* fpnb = ws + off;   // 8*256*16384 floats max

    // 1. lateral 1x1 convs
    for (int i = 0; i < 5; ++i) {
        const int N = 8 * HW[i];
        dim3 g(N / 128, 2);
        conv_gemm<1, false, 0><<<g, 256, 0, stream>>>(
            f[i], lat_w[i], lat_b + i * 256,
            nullptr, nullptr, nullptr, nullptr, lat[i],
            Cin[i], Cin[i], logS[i], logHW[i], N, 256, 0, 0);
    }

    // 2. top-down pathway (sequential: i=4..1)
    for (int i = 4; i >= 1; --i) {
        const int n = 8 * 256 * HW[i - 1];
        upsample_add_k<<<dim3((n + 255) / 256), 256, 0, stream>>>(
            lat[i - 1], lat[i], logS[i - 1], n);
    }

    // 3+4. per level: fpn 3x3 conv, then both heads
    for (int i = 0; i < 5; ++i) {
        const int N = 8 * HW[i];
        dim3 gc(N / 128, 2);
        dim3 gh(N / 128, 1);
        // fpn conv
        conv_gemm<3, false, 0><<<gc, 256, 0, stream>>>(
            lat[i], fpn_w + (size_t)i * 256 * 2304, fpn_b + i * 256,
            nullptr, nullptr, nullptr, nullptr, fpnb,
            256, 2304, logS[i], logHW[i], N, 256, 0, 0);
        // cls head: 3x3 conv + BN + ReLU (tmp reuses lat[i]), then 1x1 -> out
        conv_gemm<3, true, 0><<<gc, 256, 0, stream>>>(
            fpnb, cls_w1, cls_b1, cls_g, cls_bt, cls_m, cls_v, lat[i],
            256, 2304, logS[i], logHW[i], N, 256, 0, 0);
        conv_gemm<1, false, 10><<<gh, 256, 0, stream>>>(
            lat[i], cls_w2, cls_b2,
            nullptr, nullptr, nullptr, nullptr, out,
            256, 256, logS[i], logHW[i], N, 90, abase[i], 4);
        // reg head
        conv_gemm<3, true, 0><<<gc, 256, 0, stream>>>(
            fpnb, reg_w1, reg_b1, reg_g, reg_bt, reg_m, reg_v, lat[i],
            256, 2304, logS[i], logHW[i], N, 256, 0, 0);
        conv_gemm<1, false, 4><<<gh, 256, 0, stream>>>(
            lat[i], reg_w2, reg_b2,
            nullptr, nullptr, nullptr, nullptr, out,
            256, 256, logS[i], logHW[i], N, 36, abase[i], 0);
    }
}

// Round 3
// 4602.956 us; speedup vs baseline: 2.8358x; 2.8358x over previous
//
#include <hip/hip_runtime.h>

// ---------------------------------------------------------------------------
// EfficientDet head on MFMA (gfx950), split-bf16 (hi+lo) fp32-accurate GEMM.
// All convs = implicit GEMM: C[co][n] = W[co][k] * Im2col[k][n].
// Activations: NHWC bf16 hi/lo planes; 3x3 inputs spatially zero-padded P=S+2.
// K order for 3x3: k = (r*3+s)*256 + ci  (tap-major -> contiguous ci chunks).
// 3 MFMAs per tile-pair: AhiBhi + AhiBlo + AloBhi  (error ~2^-17 relative).
// WS budget: 187 MB lat planes + 69 MB shared transient arena + 17 MB weights
//            = 273.6 MB  (round-1 proved >= 313 MB is available; 372 MB faulted)
// Level-0 fpn/head phase runs in two 4-image groups so its padded fpn planes
// fit the shared arena.
// ---------------------------------------------------------------------------

typedef unsigned short ush;
typedef __attribute__((ext_vector_type(8))) short v8s;
typedef __attribute__((ext_vector_type(4))) float v4f;

constexpr int TOTAL_ANCH = 196416;  // 9 * (128^2+64^2+32^2+16^2+8^2)

__device__ __forceinline__ ush f2bf(float x) {
    unsigned u = __builtin_bit_cast(unsigned, x);
    u += 0x7FFFu + ((u >> 16) & 1u);
    return (ush)(u >> 16);
}
__device__ __forceinline__ float bf2f(ush h) {
    unsigned u = ((unsigned)h) << 16;
    return __builtin_bit_cast(float, u);
}
__device__ __forceinline__ void splitf(float x, ush& hi, ush& lo) {
    hi = f2bf(x);
    lo = f2bf(x - bf2f(hi));
}

// ---------------------------------------------------------------------------
// Core MFMA conv kernel.
// KS: 1 (1x1, unpadded NHWC in, stride Kin) or 3 (3x3, padded NHWC in, stride 256)
// OM: 0 = padded NHWC hi/lo out; 1 = unpadded NHWC hi/lo out; 2 = scatter fp32 out
// BNR: fused BN+ReLU.  DD: out_dim for scatter (4 or 10).
// ibase: image offset added to the local batch index in the scatter epilogue.
// ---------------------------------------------------------------------------
template <int KS, int OM, bool BNR, int DD>
__global__ __launch_bounds__(256, 2)
void conv_mfma(const ush* __restrict__ Xh, const ush* __restrict__ Xl,
               const ush* __restrict__ Wh, const ush* __restrict__ Wl,
               const float* __restrict__ bias,
               const float* __restrict__ bng, const float* __restrict__ bnb,
               const float* __restrict__ bnm, const float* __restrict__ bnv,
               ush* __restrict__ Yh, ush* __restrict__ Yl,
               float* __restrict__ Yf,
               int K, int logS, int logHW, int Kin, int Cout,
               int abase, int coloff, int ibase)
{
    const int tid = threadIdx.x;
    const int n0  = blockIdx.x * 128;
    const int co0 = blockIdx.y * 128;
    const int S = 1 << logS, HW = 1 << logHW, P = S + 2;

    __shared__ short As[128][72];   // [co ][ k: hi 0..31 | lo 32..63 | pad ]
    __shared__ short Bs[128][72];   // [pix][ k: hi 0..31 | lo 32..63 | pad ]

    const int lane = tid & 63;
    const int w = tid >> 6;
    const int wm = w & 1, wn = w >> 1;     // wave grid 2(M) x 2(N), 64x64/wave
    const int l15 = lane & 15, l4 = lane >> 4;

    // staging: thread owns one row (co for A, pixel for B), one 16B k-segment
    const int arow = tid & 127;
    const int seg  = tid >> 7;

    const bool aok = (co0 + arow) < Cout;
    const int abase_e = (co0 + arow) * K + seg * 8;

    const int bn  = n0 + arow;
    const int bb  = bn >> logHW;
    const int bhw = bn & (HW - 1);
    int bbase_e;
    if (KS == 3) {
        const int oh = bhw >> logS, ow = bhw & (S - 1);
        bbase_e = ((bb * P + oh + 1) * P + ow + 1) * 256 + seg * 8;
    } else {
        bbase_e = bn * Kin + seg * 8;
    }

    const int KC = K >> 5;   // K always a multiple of 32

    int4 ra0, ra1, ra2, ra3, rb0, rb1, rb2, rb3;
    auto gload = [&](int c) {
        const int ae = abase_e + c * 32;
        if (aok) {
            ra0 = *(const int4*)(Wh + ae);
            ra1 = *(const int4*)(Wh + ae + 16);
            ra2 = *(const int4*)(Wl + ae);
            ra3 = *(const int4*)(Wl + ae + 16);
        } else {
            ra0 = make_int4(0,0,0,0); ra1 = ra0; ra2 = ra0; ra3 = ra0;
        }
        int be;
        if (KS == 3) {
            const int rs = c >> 3;            // tap index (wave-uniform)
            const int cio = (c & 7) * 32;     // ci offset within tap
            const int r = rs / 3, s = rs - 3 * r;
            be = bbase_e + ((r - 1) * P + (s - 1)) * 256 + cio;
        } else {
            be = bbase_e + c * 32;
        }
        rb0 = *(const int4*)(Xh + be);
        rb1 = *(const int4*)(Xh + be + 16);
        rb2 = *(const int4*)(Xl + be);
        rb3 = *(const int4*)(Xl + be + 16);
    };

    v4f acc[4][4] = {};

    gload(0);
    for (int c = 0; c < KC; ++c) {
        __syncthreads();     // previous chunk's compute done
        *(int4*)&As[arow][seg * 8]          = ra0;
        *(int4*)&As[arow][seg * 8 + 16]     = ra1;
        *(int4*)&As[arow][32 + seg * 8]     = ra2;
        *(int4*)&As[arow][32 + seg * 8 + 16]= ra3;
        *(int4*)&Bs[arow][seg * 8]          = rb0;
        *(int4*)&Bs[arow][seg * 8 + 16]     = rb1;
        *(int4*)&Bs[arow][32 + seg * 8]     = rb2;
        *(int4*)&Bs[arow][32 + seg * 8 + 16]= rb3;
        __syncthreads();
        if (c + 1 < KC) gload(c + 1);   // prefetch overlaps with MFMA below

        v8s ah[4], al[4];
#pragma unroll
        for (int i = 0; i < 4; ++i) {
            ah[i] = *(const v8s*)&As[wm * 64 + i * 16 + l15][l4 * 8];
            al[i] = *(const v8s*)&As[wm * 64 + i * 16 + l15][32 + l4 * 8];
        }
#pragma unroll
        for (int j = 0; j < 4; ++j) {
            const v8s bh = *(const v8s*)&Bs[wn * 64 + j * 16 + l15][l4 * 8];
            const v8s bl = *(const v8s*)&Bs[wn * 64 + j * 16 + l15][32 + l4 * 8];
#pragma unroll
            for (int i = 0; i < 4; ++i) {
                acc[i][j] = __builtin_amdgcn_mfma_f32_16x16x32_bf16(ah[i], bh, acc[i][j], 0, 0, 0);
                acc[i][j] = __builtin_amdgcn_mfma_f32_16x16x32_bf16(ah[i], bl, acc[i][j], 0, 0, 0);
                acc[i][j] = __builtin_amdgcn_mfma_f32_16x16x32_bf16(al[i], bh, acc[i][j], 0, 0, 0);
            }
        }
    }

    // ---- epilogue: C layout col = lane&15 (pixel), row = (lane>>4)*4+e (co) ----
#pragma unroll
    for (int i = 0; i < 4; ++i) {
        const int cob = wm * 64 + i * 16 + l4 * 4;
        const int co  = co0 + cob;
        float sc[4], sh[4];
#pragma unroll
        for (int e = 0; e < 4; ++e) {
            if (OM == 2) {
                sc[e] = 1.f;
                sh[e] = (co + e < Cout) ? bias[co + e] : 0.f;
            } else if (BNR) {
                const float inv = bng[co + e] * rsqrtf(bnv[co + e] + 1e-5f);
                sc[e] = inv;
                sh[e] = (bias[co + e] - bnm[co + e]) * inv + bnb[co + e];
            } else {
                sc[e] = 1.f; sh[e] = bias[co + e];
            }
        }
#pragma unroll
        for (int j = 0; j < 4; ++j) {
            const int ncol = n0 + wn * 64 + j * 16 + l15;
            const int b  = ncol >> logHW;
            const int hw = ncol & (HW - 1);
            float val[4];
#pragma unroll
            for (int e = 0; e < 4; ++e) {
                float x = acc[i][j][e] * sc[e] + sh[e];
                if (BNR) x = fmaxf(x, 0.f);
                val[e] = x;
            }
            if (OM == 2) {
#pragma unroll
                for (int e = 0; e < 4; ++e) {
                    const int c2 = co + e;
                    if (c2 < Cout) {
                        const int a = c2 / DD, cl = c2 - a * DD;
                        Yf[(size_t)((b + ibase) * TOTAL_ANCH + abase + hw * 9 + a) * 14
                           + coloff + cl] = val[e];
                    }
                }
            } else {
                int pidx;
                if (OM == 0) {
                    const int oh = hw >> logS, ow = hw & (S - 1);
                    pidx = (b * P + oh + 1) * P + ow + 1;
                } else {
                    pidx = ncol;
                }
                const int addr = pidx * 256 + co;
                ush hs[4], ls[4];
#pragma unroll
                for (int e = 0; e < 4; ++e) splitf(val[e], hs[e], ls[e]);
                *(uint2*)&Yh[addr] = make_uint2(hs[0] | ((unsigned)hs[1] << 16),
                                                hs[2] | ((unsigned)hs[3] << 16));
                *(uint2*)&Yl[addr] = make_uint2(ls[0] | ((unsigned)ls[1] << 16),
                                                ls[2] | ((unsigned)ls[3] << 16));
            }
        }
    }
}

// ---- prep / glue kernels -------------------------------------------------

// 3x3 weights: [co5][ci][r][s] fp32 -> hi/lo [co5][ (r*3+s)*256 + ci ]
__global__ void w3_prep(const float* __restrict__ W, ush* __restrict__ wh,
                        ush* __restrict__ wl, int total) {
    const int idx = blockIdx.x * 256 + threadIdx.x;
    if (idx >= total) return;
    const int co5 = idx / 2304;
    const int kk  = idx - co5 * 2304;
    const int rs = kk >> 8, ci = kk & 255;
    splitf(W[(co5 * 256 + ci) * 9 + rs], wh[idx], wl[idx]);
}

// 1x1 weights: [co][Cin] fp32 -> hi/lo [co][Kp] (ci zero-padded)
__global__ void w1_prep(const float* __restrict__ W, ush* __restrict__ wh,
                        ush* __restrict__ wl, int Cin, int Kp, int total) {
    const int idx = blockIdx.x * 256 + threadIdx.x;
    if (idx >= total) return;
    const int co = idx / Kp;
    const int k  = idx - co * Kp;
    const float x = (k < Cin) ? W[co * Cin + k] : 0.f;
    splitf(x, wh[idx], wl[idx]);
}

// NCHW fp32 input -> unpadded NHWC hi/lo, ci zero-padded to Kp
__global__ void in_prep(const float* __restrict__ f, ush* __restrict__ xh,
                        ush* __restrict__ xl, int Cin, int Kp, int logHW, int total) {
    const int idx = blockIdx.x * 256 + threadIdx.x;
    if (idx >= total) return;
    const int c = idx % Kp;
    const int n = idx / Kp;
    const int b  = n >> logHW;
    const int hw = n & ((1 << logHW) - 1);
    const float x = (c < Cin) ? f[((b * Cin + c) << logHW) + hw] : 0.f;
    splitf(x, xh[idx], xl[idx]);
}

// fine (padded NHWC hi/lo) += nearest-upsampled coarse (padded NHWC hi/lo)
__global__ void upsample_hl(ush* __restrict__ fh, ush* __restrict__ fl,
                            const ush* __restrict__ ch, const ush* __restrict__ cl2,
                            int logSf, int total) {
    const int idx = blockIdx.x * 256 + threadIdx.x;
    if (idx >= total) return;
    const int ci = idx & 255;
    const int r  = idx >> 8;
    const int Sf = 1 << logSf;
    const int wf = r & (Sf - 1);
    const int hf = (r >> logSf) & (Sf - 1);
    const int b  = r >> (2 * logSf);
    const int Pf = Sf + 2, Pc = (Sf >> 1) + 2;
    const int fi = ((b * Pf + hf + 1) * Pf + wf + 1) * 256 + ci;
    const int cx = ((b * Pc + (hf >> 1) + 1) * Pc + (wf >> 1) + 1) * 256 + ci;
    const float x = bf2f(fh[fi]) + bf2f(fl[fi]) + bf2f(ch[cx]) + bf2f(cl2[cx]);
    splitf(x, fh[fi], fl[fi]);
}

// zero the pad ring of a padded NHWC hi/lo pair (nimg images inferred from total)
__global__ void ring_zero(ush* __restrict__ yh, ush* __restrict__ yl, int S, int total) {
    const int idx = blockIdx.x * 256 + threadIdx.x;
    if (idx >= total) return;
    const int ci = idx & 255;
    const int r  = idx >> 8;
    const int P = S + 2;
    const int ring = 4 * P - 4;
    const int pr = r % ring;
    const int b  = r / ring;
    int ph, pw;
    if (pr < P)            { ph = 0;     pw = pr; }
    else if (pr < 2 * P)   { ph = P - 1; pw = pr - P; }
    else { const int q = pr - 2 * P; ph = 1 + (q >> 1); pw = (q & 1) ? (P - 1) : 0; }
    const int a = ((b * P + ph) * P + pw) * 256 + ci;
    yh[a] = 0; yl[a] = 0;
}

// ---------------------------------------------------------------------------

extern "C" void kernel_launch(void* const* d_in, const int* in_sizes, int n_in,
                              void* d_out, int out_size, void* d_ws, size_t ws_size,
                              hipStream_t stream)
{
    const float* f[5];     const float* lat_w[5];
    for (int i = 0; i < 5; ++i) f[i] = (const float*)d_in[i];
    for (int i = 0; i < 5; ++i) lat_w[i] = (const float*)d_in[5 + i];
    const float* lat_b  = (const float*)d_in[10];
    const float* fpn_w  = (const float*)d_in[11];
    const float* fpn_b  = (const float*)d_in[12];
    const float* cls_w1 = (const float*)d_in[13];
    const float* cls_b1 = (const float*)d_in[14];
    const float* cls_g  = (const float*)d_in[15];
    const float* cls_bt = (const float*)d_in[16];
    const float* cls_m  = (const float*)d_in[17];
    const float* cls_v  = (const float*)d_in[18];
    const float* cls_w2 = (const float*)d_in[19];
    const float* cls_b2 = (const float*)d_in[20];
    const float* reg_w1 = (const float*)d_in[21];
    const float* reg_b1 = (const float*)d_in[22];
    const float* reg_g  = (const float*)d_in[23];
    const float* reg_bt = (const float*)d_in[24];
    const float* reg_m  = (const float*)d_in[25];
    const float* reg_v  = (const float*)d_in[26];
    const float* reg_w2 = (const float*)d_in[27];
    const float* reg_b2 = (const float*)d_in[28];

    float* out = (float*)d_out;
    ush*   ws16 = (ush*)d_ws;

    static const int S_[5]     = {128, 64, 32, 16, 8};
    static const int logS_[5]  = {7, 6, 5, 4, 3};
    static const int logHW_[5] = {14, 12, 10, 8, 6};
    static const int HW_[5]    = {16384, 4096, 1024, 256, 64};
    static const int Cin_[5]   = {32, 48, 96, 136, 232};
    static const int Kp_[5]    = {32, 64, 96, 160, 256};
    static const int abase_[5] = {0, 147456, 184320, 193536, 195840};

    size_t off = 0;
    auto alloc = [&](size_t elems) {
        ush* p = ws16 + off;
        off += (elems + 63) & ~(size_t)63;
        return p;
    };

    // --- persistent: padded lateral planes (reused as head-conv1 tmp) ---
    ush *lat_h[5], *lat_l[5];
    for (int i = 0; i < 5; ++i) {
        const int P = S_[i] + 2;
        const size_t e = (size_t)2048 * P * P;   // 8 images * P*P * 256
        lat_h[i] = alloc(e); lat_l[i] = alloc(e);
    }
    const size_t lat_bytes = off * sizeof(ush);

    // --- shared transient arena (69.2 MB): input conversion planes, then
    //     per-level fpn planes (levels 1-4 whole batch; level 0 in 4-image
    //     groups). 4 images * 130*130 * 256 * 2 planes.
    const size_t ARENA_E = (size_t)2 * 4 * 130 * 130 * 256;
    ush* arena = alloc(ARENA_E);

    // --- weights ---
    ush* fw_h = alloc((size_t)5 * 256 * 2304); ush* fw_l = alloc((size_t)5 * 256 * 2304);
    ush* cw_h = alloc(256 * 2304);             ush* cw_l = alloc(256 * 2304);
    ush* rw_h = alloc(256 * 2304);             ush* rw_l = alloc(256 * 2304);
    ush *lw_h[5], *lw_l[5];
    for (int i = 0; i < 5; ++i) { lw_h[i] = alloc(256 * Kp_[i]); lw_l[i] = alloc(256 * Kp_[i]); }
    ush* c2_h = alloc(90 * 256); ush* c2_l = alloc(90 * 256);
    ush* r2_h = alloc(36 * 256); ush* r2_l = alloc(36 * 256);
    // total: 136,780,800 elems = 273.6 MB

    // zero padded lateral arena (pads must be 0; ws is re-poisoned every call)
    hipMemsetAsync(ws16, 0, lat_bytes, stream);

    // --- weight prep ---
    {
        int t = 5 * 256 * 2304;
        w3_prep<<<dim3((t + 255) / 256), 256, 0, stream>>>(fpn_w, fw_h, fw_l, t);
        t = 256 * 2304;
        w3_prep<<<dim3((t + 255) / 256), 256, 0, stream>>>(cls_w1, cw_h, cw_l, t);
        w3_prep<<<dim3((t + 255) / 256), 256, 0, stream>>>(reg_w1, rw_h, rw_l, t);
        for (int i = 0; i < 5; ++i) {
            t = 256 * Kp_[i];
            w1_prep<<<dim3((t + 255) / 256), 256, 0, stream>>>(lat_w[i], lw_h[i], lw_l[i], Cin_[i], Kp_[i], t);
        }
        t = 90 * 256;
        w1_prep<<<dim3((t + 255) / 256), 256, 0, stream>>>(cls_w2, c2_h, c2_l, 256, 256, t);
        t = 36 * 256;
        w1_prep<<<dim3((t + 255) / 256), 256, 0, stream>>>(reg_w2, r2_h, r2_l, 256, 256, t);
    }

    // --- input conversion + lateral 1x1 convs (arena reused per level) ---
    for (int i = 0; i < 5; ++i) {
        const int N = 8 * HW_[i];
        const int t = N * Kp_[i];
        ush* xh = arena;
        ush* xl = arena + (size_t)N * Kp_[i];
        in_prep<<<dim3((t + 255) / 256), 256, 0, stream>>>(f[i], xh, xl, Cin_[i], Kp_[i], logHW_[i], t);
        conv_mfma<1, 0, false, 0><<<dim3(N / 128, 2), 256, 0, stream>>>(
            xh, xl, lw_h[i], lw_l[i], lat_b + i * 256,
            nullptr, nullptr, nullptr, nullptr,
            lat_h[i], lat_l[i], nullptr,
            Kp_[i], logS_[i], logHW_[i], Kp_[i], 256, 0, 0, 0);
    }

    // --- top-down pathway ---
    for (int i = 4; i >= 1; --i) {
        const int t = 8 * HW_[i - 1] * 256;
        upsample_hl<<<dim3((t + 255) / 256), 256, 0, stream>>>(
            lat_h[i - 1], lat_l[i - 1], lat_h[i], lat_l[i], logS_[i - 1], t);
    }

    // --- levels 1..4: whole-batch fpn + heads (fpn planes in arena) ---
    for (int i = 1; i < 5; ++i) {
        const int N = 8 * HW_[i];
        const int P = S_[i] + 2;
        ush* fpn_h = arena;
        ush* fpn_l = arena + (size_t)8 * P * P * 256;
        const int rt = 8 * (4 * P - 4) * 256;
        ring_zero<<<dim3((rt + 255) / 256), 256, 0, stream>>>(fpn_h, fpn_l, S_[i], rt);

        conv_mfma<3, 0, false, 0><<<dim3(N / 128, 2), 256, 0, stream>>>(
            lat_h[i], lat_l[i], fw_h + (size_t)i * 256 * 2304, fw_l + (size_t)i * 256 * 2304,
            fpn_b + i * 256, nullptr, nullptr, nullptr, nullptr,
            fpn_h, fpn_l, nullptr, 2304, logS_[i], logHW_[i], 256, 256, 0, 0, 0);

        conv_mfma<3, 1, true, 0><<<dim3(N / 128, 2), 256, 0, stream>>>(
            fpn_h, fpn_l, cw_h, cw_l, cls_b1, cls_g, cls_bt, cls_m, cls_v,
            lat_h[i], lat_l[i], nullptr, 2304, logS_[i], logHW_[i], 256, 256, 0, 0, 0);
        conv_mfma<1, 2, false, 10><<<dim3(N / 128, 1), 256, 0, stream>>>(
            lat_h[i], lat_l[i], c2_h, c2_l, cls_b2,
            nullptr, nullptr, nullptr, nullptr, nullptr, nullptr, out,
            256, logS_[i], logHW_[i], 256, 90, abase_[i], 4, 0);

        conv_mfma<3, 1, true, 0><<<dim3(N / 128, 2), 256, 0, stream>>>(
            fpn_h, fpn_l, rw_h, rw_l, reg_b1, reg_g, reg_bt, reg_m, reg_v,
            lat_h[i], lat_l[i], nullptr, 2304, logS_[i], logHW_[i], 256, 256, 0, 0, 0);
        conv_mfma<1, 2, false, 4><<<dim3(N / 128, 1), 256, 0, stream>>>(
            lat_h[i], lat_l[i], r2_h, r2_l, reg_b2,
            nullptr, nullptr, nullptr, nullptr, nullptr, nullptr, out,
            256, logS_[i], logHW_[i], 256, 36, abase_[i], 0, 0);
    }

    // --- level 0: two 4-image groups ---
    {
        const int P = 130;
        const size_t padg = (size_t)4 * P * P * 256;     // padded, 4 images
        const size_t unpg = (size_t)4 * 16384 * 256;     // unpadded, 4 images
        for (int g = 0; g < 2; ++g) {
            const int N = 4 * 16384;                     // 65536 pixels/group
            ush* fpn_h = arena;
            ush* fpn_l = arena + padg;
            ush* lat0p_h = lat_h[0] + (size_t)g * padg;  // group's padded lat input
            ush* lat0p_l = lat_l[0] + (size_t)g * padg;
            ush* tmp_h   = lat_h[0] + (size_t)g * unpg;  // group's head tmp (unpadded)
            ush* tmp_l   = lat_l[0] + (size_t)g * unpg;
            const int rt = 4 * (4 * P - 4) * 256;
            ring_zero<<<dim3((rt + 255) / 256), 256, 0, stream>>>(fpn_h, fpn_l, 128, rt);

            conv_mfma<3, 0, false, 0><<<dim3(N / 128, 2), 256, 0, stream>>>(
                lat0p_h, lat0p_l, fw_h, fw_l, fpn_b,
                nullptr, nullptr, nullptr, nullptr,
                fpn_h, fpn_l, nullptr, 2304, 7, 14, 256, 256, 0, 0, 0);

            conv_mfma<3, 1, true, 0><<<dim3(N / 128, 2), 256, 0, stream>>>(
                fpn_h, fpn_l, cw_h, cw_l, cls_b1, cls_g, cls_bt, cls_m, cls_v,
                tmp_h, tmp_l, nullptr, 2304, 7, 14, 256, 256, 0, 0, 0);
            conv_mfma<1, 2, false, 10><<<dim3(N / 128, 1), 256, 0, stream>>>(
                tmp_h, tmp_l, c2_h, c2_l, cls_b2,
                nullptr, nullptr, nullptr, nullptr, nullptr, nullptr, out,
                256, 7, 14, 256, 90, 0, 4, 4 * g);

            conv_mfma<3, 1, true, 0><<<dim3(N / 128, 2), 256, 0, stream>>>(
                fpn_h, fpn_l, rw_h, rw_l, reg_b1, reg_g, reg_bt, reg_m, reg_v,
                tmp_h, tmp_l, nullptr, 2304, 7, 14, 256, 256, 0, 0, 0);
            conv_mfma<1, 2, false, 4><<<dim3(N / 128, 1), 256, 0, stream>>>(
                tmp_h, tmp_l, r2_h, r2_l, reg_b2,
                nullptr, nullptr, nullptr, nullptr, nullptr, nullptr, out,
                256, 7, 14, 256, 36, 0, 0, 4 * g);
        }
    }
}